// Round 1
// baseline (275.817 us; speedup 1.0000x reference)
//
#include <hip/hip_runtime.h>

#define HID 20

// fast tanh via hardware exp: tanh(v) = 1 - 2/(e^{2v}+1); saturates correctly at +-inf
static __device__ __forceinline__ float tanh_fast(float v) {
    float e = __expf(2.0f * v);
    return 1.0f - 2.0f / (e + 1.0f);
}

struct WeightsLDS {
    float W1[2 * HID];   // [2][20] row-major (fan_in, fan_out)
    float b1[HID];
    float W2[HID * HID]; // [20][20]
    float b2[HID];
    float W3[HID * HID];
    float b3[HID];
    float W4[HID];       // [20][1]
    float b4;
};

__device__ __forceinline__ void load_weights(WeightsLDS& w,
    const float* __restrict__ W1, const float* __restrict__ b1,
    const float* __restrict__ W2, const float* __restrict__ b2,
    const float* __restrict__ W3, const float* __restrict__ b3,
    const float* __restrict__ W4, const float* __restrict__ b4)
{
    const int tid = threadIdx.x;
    for (int k = tid; k < 2 * HID; k += 256)   w.W1[k] = W1[k];
    for (int k = tid; k < HID; k += 256)       w.b1[k] = b1[k];
    for (int k = tid; k < HID * HID; k += 256) w.W2[k] = W2[k];
    for (int k = tid; k < HID; k += 256)       w.b2[k] = b2[k];
    for (int k = tid; k < HID * HID; k += 256) w.W3[k] = W3[k];
    for (int k = tid; k < HID; k += 256)       w.b3[k] = b3[k];
    for (int k = tid; k < HID; k += 256)       w.W4[k] = W4[k];
    if (tid == 0) w.b4 = b4[0];
    __syncthreads();
}

// 64-lane shuffle reduce -> cross-wave LDS -> one f64 atomic per block
__device__ __forceinline__ void block_reduce_atomic(float local, double* dst) {
    #pragma unroll
    for (int off = 32; off > 0; off >>= 1) local += __shfl_down(local, off);
    __shared__ float parts[4];
    const int lane = threadIdx.x & 63, wid = threadIdx.x >> 6;
    if (lane == 0) parts[wid] = local;
    __syncthreads();
    if (threadIdx.x == 0) {
        atomicAdd(dst, (double)(parts[0] + parts[1] + parts[2] + parts[3]));
    }
}

// One hidden layer with 4-channel dual numbers (value, d/dt, d/dx, d2/dx2).
// j blocked by 4 so W[i][j..j+3] fuses into ds_read_b128.
__device__ __forceinline__ void layer_dual(
    const float* __restrict__ W, const float* __restrict__ b,
    const float (&h)[HID], const float (&ha)[HID],
    const float (&hc)[HID], const float (&he)[HID],
    float (&nh)[HID], float (&nha)[HID], float (&nhc)[HID], float (&nhe)[HID])
{
    #pragma unroll
    for (int j0 = 0; j0 < HID; j0 += 4) {
        float av[4], aa[4], ac[4], ae[4];
        #pragma unroll
        for (int k = 0; k < 4; ++k) { av[k] = b[j0 + k]; aa[k] = 0.f; ac[k] = 0.f; ae[k] = 0.f; }
        #pragma unroll
        for (int i = 0; i < HID; ++i) {
            #pragma unroll
            for (int k = 0; k < 4; ++k) {
                const float wv = W[i * HID + j0 + k];
                av[k] = fmaf(wv, h[i],  av[k]);
                aa[k] = fmaf(wv, ha[i], aa[k]);
                ac[k] = fmaf(wv, hc[i], ac[k]);
                ae[k] = fmaf(wv, he[i], ae[k]);
            }
        }
        #pragma unroll
        for (int k = 0; k < 4; ++k) {
            const float th = tanh_fast(av[k]);
            const float s  = fmaf(-th, th, 1.0f);           // sech^2
            nh[j0 + k]  = th;
            nha[j0 + k] = s * aa[k];
            nhc[j0 + k] = s * ac[k];
            // y_xx = s * p_xx - 2*y*s*(p_x)^2
            nhe[j0 + k] = fmaf(s, ae[k], -2.0f * th * s * ac[k] * ac[k]);
        }
    }
}

__global__ __launch_bounds__(256) void k_coll(
    const float* __restrict__ tc, const float* __restrict__ xc,
    const float* __restrict__ W1, const float* __restrict__ b1,
    const float* __restrict__ W2, const float* __restrict__ b2,
    const float* __restrict__ W3, const float* __restrict__ b3,
    const float* __restrict__ W4, const float* __restrict__ b4,
    double* __restrict__ sum_out, int N, float nu)
{
    __shared__ WeightsLDS w;
    load_weights(w, W1, b1, W2, b2, W3, b3, W4, b4);

    const int idx = blockIdx.x * 256 + threadIdx.x;
    float local = 0.0f;
    if (idx < N) {
        const float tv = tc[idx], xv = xc[idx];
        float h[HID], ha[HID], hc[HID], he[HID];
        // layer 1: p = t*W1[0][j] + x*W1[1][j] + b1[j]; p_t = W1[0][j]; p_x = W1[1][j]; p_xx = 0
        #pragma unroll
        for (int j = 0; j < HID; ++j) {
            const float w0 = w.W1[j];
            const float w1 = w.W1[HID + j];
            const float p  = fmaf(tv, w0, fmaf(xv, w1, w.b1[j]));
            const float th = tanh_fast(p);
            const float s  = fmaf(-th, th, 1.0f);
            h[j]  = th;
            ha[j] = s * w0;
            hc[j] = s * w1;
            he[j] = -2.0f * th * s * w1 * w1;
        }
        float g[HID], ga[HID], gc[HID], ge[HID];
        layer_dual(w.W2, w.b2, h, ha, hc, he, g, ga, gc, ge);
        layer_dual(w.W3, w.b3, g, ga, gc, ge, h, ha, hc, he);
        // output layer (linear)
        float u = w.b4, ut = 0.f, ux = 0.f, uxx = 0.f;
        #pragma unroll
        for (int i = 0; i < HID; ++i) {
            const float wv = w.W4[i];
            u   = fmaf(wv, h[i],  u);
            ut  = fmaf(wv, ha[i], ut);
            ux  = fmaf(wv, hc[i], ux);
            uxx = fmaf(wv, he[i], uxx);
        }
        const float f = fmaf(u, ux, ut) - nu * uxx;
        local = f * f;
    }
    block_reduce_atomic(local, sum_out);
}

// value-only forward for initial/boundary residuals
__global__ __launch_bounds__(256) void k_data(
    const float* __restrict__ tt, const float* __restrict__ xx,
    const float* __restrict__ utrue,
    const float* __restrict__ W1, const float* __restrict__ b1,
    const float* __restrict__ W2, const float* __restrict__ b2,
    const float* __restrict__ W3, const float* __restrict__ b3,
    const float* __restrict__ W4, const float* __restrict__ b4,
    double* __restrict__ sum_out, int n)
{
    __shared__ WeightsLDS w;
    load_weights(w, W1, b1, W2, b2, W3, b3, W4, b4);

    const int idx = blockIdx.x * 256 + threadIdx.x;
    float local = 0.0f;
    if (idx < n) {
        const float tv = tt[idx], xv = xx[idx];
        float h[HID], g[HID];
        #pragma unroll
        for (int j = 0; j < HID; ++j)
            h[j] = tanh_fast(fmaf(tv, w.W1[j], fmaf(xv, w.W1[HID + j], w.b1[j])));
        #pragma unroll
        for (int j0 = 0; j0 < HID; j0 += 4) {
            float acc[4];
            #pragma unroll
            for (int k = 0; k < 4; ++k) acc[k] = w.b2[j0 + k];
            #pragma unroll
            for (int i = 0; i < HID; ++i) {
                #pragma unroll
                for (int k = 0; k < 4; ++k)
                    acc[k] = fmaf(w.W2[i * HID + j0 + k], h[i], acc[k]);
            }
            #pragma unroll
            for (int k = 0; k < 4; ++k) g[j0 + k] = tanh_fast(acc[k]);
        }
        #pragma unroll
        for (int j0 = 0; j0 < HID; j0 += 4) {
            float acc[4];
            #pragma unroll
            for (int k = 0; k < 4; ++k) acc[k] = w.b3[j0 + k];
            #pragma unroll
            for (int i = 0; i < HID; ++i) {
                #pragma unroll
                for (int k = 0; k < 4; ++k)
                    acc[k] = fmaf(w.W3[i * HID + j0 + k], g[i], acc[k]);
            }
            #pragma unroll
            for (int k = 0; k < 4; ++k) h[j0 + k] = tanh_fast(acc[k]);
        }
        float u = w.b4;
        #pragma unroll
        for (int i = 0; i < HID; ++i) u = fmaf(w.W4[i], h[i], u);
        const float d = u - utrue[idx];
        local = d * d;
    }
    block_reduce_atomic(local, sum_out);
}

__global__ void k_zero(double* sums) {
    if (threadIdx.x < 3) sums[threadIdx.x] = 0.0;
}

__global__ void k_fin(const double* __restrict__ sums, float* __restrict__ out,
                      int N, int NI, int NB) {
    out[0] = (float)(sums[0] / (double)N + sums[1] / (double)NI + sums[2] / (double)NB);
}

extern "C" void kernel_launch(void* const* d_in, const int* in_sizes, int n_in,
                              void* d_out, int out_size, void* d_ws, size_t ws_size,
                              hipStream_t stream) {
    const float* t_c = (const float*)d_in[0];
    const float* x_c = (const float*)d_in[1];
    const float* t_i = (const float*)d_in[2];
    const float* x_i = (const float*)d_in[3];
    const float* u_i = (const float*)d_in[4];
    const float* t_b = (const float*)d_in[5];
    const float* x_b = (const float*)d_in[6];
    const float* u_b = (const float*)d_in[7];
    const float* W1  = (const float*)d_in[8];
    const float* b1  = (const float*)d_in[9];
    const float* W2  = (const float*)d_in[10];
    const float* b2  = (const float*)d_in[11];
    const float* W3  = (const float*)d_in[12];
    const float* b3  = (const float*)d_in[13];
    const float* W4  = (const float*)d_in[14];
    const float* b4  = (const float*)d_in[15];

    const int N  = in_sizes[0];
    const int NI = in_sizes[2];
    const int NB = in_sizes[5];
    const float nu = 0.0031830988618379067f;  // 0.01/pi

    double* sums = (double*)d_ws;

    k_zero<<<1, 64, 0, stream>>>(sums);
    k_coll<<<(N + 255) / 256, 256, 0, stream>>>(t_c, x_c, W1, b1, W2, b2, W3, b3, W4, b4,
                                                sums + 0, N, nu);
    k_data<<<(NI + 255) / 256, 256, 0, stream>>>(t_i, x_i, u_i, W1, b1, W2, b2, W3, b3, W4, b4,
                                                 sums + 1, NI);
    k_data<<<(NB + 255) / 256, 256, 0, stream>>>(t_b, x_b, u_b, W1, b1, W2, b2, W3, b3, W4, b4,
                                                 sums + 2, NB);
    k_fin<<<1, 1, 0, stream>>>(sums, (float*)d_out, N, NI, NB);
}